// Round 11
// baseline (1556.994 us; speedup 1.0000x reference)
//
#include <hip/hip_runtime.h>
#include <hip/hip_bf16.h>
#include <math.h>

#define C_DIM 1024
#define H_DIM 4096
#define E_NUM 8

typedef __bf16 bf16x8 __attribute__((ext_vector_type(8)));
typedef float f32x4 __attribute__((ext_vector_type(4)));
typedef unsigned u32x4 __attribute__((ext_vector_type(4)));

__device__ __forceinline__ unsigned short f2bf(float f) {
  union { float f; unsigned u; } v; v.f = f;
  unsigned r = v.u + 0x7FFFu + ((v.u >> 16) & 1u);   // round-to-nearest-even
  return (unsigned short)(r >> 16);
}

__device__ __forceinline__ void gload16(const short* g, short* l) {
  __builtin_amdgcn_global_load_lds(
      (const __attribute__((address_space(1))) unsigned int*)g,
      (__attribute__((address_space(3))) unsigned int*)l, 16, 0, 0);
}

__device__ __forceinline__ f32x4 mfma16(u32x4 a, u32x4 b, f32x4 c) {
  return __builtin_amdgcn_mfma_f32_16x16x32_bf16(
      __builtin_bit_cast(bf16x8, a), __builtin_bit_cast(bf16x8, b), c, 0, 0, 0);
}

// asm ds_read_b128: invisible to the compiler LDS-DMA hazard pass.
#define DSR(v, a, imm) asm volatile("ds_read_b128 %0, %1 offset:" #imm : "=v"(v) : "v"(a))
#define LGKM0 { asm volatile("s_waitcnt lgkmcnt(0)" ::: "memory"); __builtin_amdgcn_sched_barrier(0); }
#define VMW(n) asm volatile("s_waitcnt vmcnt(" #n ")" ::: "memory")
#define LDS_U32(p) ((unsigned)(size_t)(__attribute__((address_space(3))) short*)(p))

// ---------------------------------------------------------------------------
// Router (validated rounds 1-10)
// ---------------------------------------------------------------------------
__global__ __launch_bounds__(256) void router_kernel(
    const float* __restrict__ x, const float* __restrict__ noise,
    const float* __restrict__ Wr, const float* __restrict__ Wn,
    int2* __restrict__ idx_out, float2* __restrict__ gate_out, int N)
{
  int t = blockIdx.x;
  int tid = threadIdx.x;
  const float* xrow = x + (size_t)t * C_DIM;
  float accR[E_NUM], accN[E_NUM];
#pragma unroll
  for (int e = 0; e < E_NUM; e++) { accR[e] = 0.f; accN[e] = 0.f; }
  for (int c = tid; c < C_DIM; c += 256) {
    float xv = xrow[c];
    const float* wr = Wr + (size_t)c * E_NUM;
    const float* wn = Wn + (size_t)c * E_NUM;
#pragma unroll
    for (int e = 0; e < E_NUM; e++) {
      accR[e] = fmaf(xv, wr[e], accR[e]);
      accN[e] = fmaf(xv, wn[e], accN[e]);
    }
  }
#pragma unroll
  for (int e = 0; e < E_NUM; e++) {
    for (int off = 32; off > 0; off >>= 1) {
      accR[e] += __shfl_down(accR[e], off, 64);
      accN[e] += __shfl_down(accN[e], off, 64);
    }
  }
  __shared__ float red[4][2 * E_NUM];
  int lane = tid & 63, wave = tid >> 6;
  if (lane == 0) {
#pragma unroll
    for (int e = 0; e < E_NUM; e++) { red[wave][e] = accR[e]; red[wave][E_NUM + e] = accN[e]; }
  }
  __syncthreads();
  if (tid == 0) {
    float ns[E_NUM];
#pragma unroll
    for (int e = 0; e < E_NUM; e++) {
      float lg = red[0][e] + red[1][e] + red[2][e] + red[3][e];
      float nl = red[0][E_NUM + e] + red[1][E_NUM + e] + red[2][E_NUM + e] + red[3][E_NUM + e];
      float sp = fmaxf(nl, 0.f) + log1pf(expf(-fabsf(nl)));
      ns[e] = lg + noise[(size_t)t * E_NUM + e] * sp;
    }
    int i1 = 0; float m1 = ns[0];
    int i2 = -1; float m2 = -INFINITY;
#pragma unroll
    for (int e = 1; e < E_NUM; e++) {
      float v = ns[e];
      if (v > m1) { m2 = m1; i2 = i1; m1 = v; i1 = e; }
      else if (v > m2) { m2 = v; i2 = e; }
    }
    float e2 = expf(m2 - m1);
    float s = 1.f + e2;
    gate_out[t] = make_float2(1.f / s, e2 / s);
    idx_out[t] = make_int2(i1, i2);
  }
}

// ---------------------------------------------------------------------------
// Capacity scan (validated) + per-expert kept count
// ---------------------------------------------------------------------------
__global__ __launch_bounds__(256) void scan_kernel(
    const int2* __restrict__ idx, const float2* __restrict__ gates,
    int* __restrict__ s2t, float* __restrict__ gslot, int* __restrict__ counts,
    int N, int cap)
{
  int e = blockIdx.x;
  int tid = threadIdx.x;
  for (int s = tid; s < cap; s += 256) { s2t[(size_t)e * cap + s] = N; gslot[(size_t)e * cap + s] = 0.f; }
  __syncthreads();
  __shared__ int wtot[4];
  int lane = tid & 63, wave = tid >> 6;
  int running = 0;
  for (int base = 0; base < N; base += 256) {
    int t = base + tid;
    int2 ix = idx[t];
    bool flag = (ix.x == e) || (ix.y == e);
    unsigned long long m = __ballot(flag);
    int rank = __popcll(m & ((1ull << lane) - 1ull));
    if (lane == 0) wtot[wave] = __popcll(m);
    __syncthreads();
    int woff = 0;
    for (int w = 0; w < wave; w++) woff += wtot[w];
    int slot = running + woff + rank;
    if (flag && slot < cap) {
      s2t[(size_t)e * cap + slot] = t;
      gslot[(size_t)e * cap + slot] = (ix.x == e) ? gates[t].x : gates[t].y;
    }
    running += wtot[0] + wtot[1] + wtot[2] + wtot[3];
    __syncthreads();
  }
  if (tid == 0) counts[e] = min(running, cap);
}

// ---------------------------------------------------------------------------
// f32 -> bf16, 8 elems/thread (validated)
// ---------------------------------------------------------------------------
__global__ __launch_bounds__(256) void convert_x_kernel(
    const float* __restrict__ src, short* __restrict__ dst, int n8)
{
  int i = blockIdx.x * 256 + threadIdx.x;
  if (i >= n8) return;
  const float4* s = (const float4*)src + (size_t)i * 2;
  float4 a = s[0], b = s[1];
  union { unsigned short us[8]; uint4 v; } o;
  o.us[0] = f2bf(a.x); o.us[1] = f2bf(a.y); o.us[2] = f2bf(a.z); o.us[3] = f2bf(a.w);
  o.us[4] = f2bf(b.x); o.us[5] = f2bf(b.y); o.us[6] = f2bf(b.z); o.us[7] = f2bf(b.w);
  ((uint4*)dst)[i] = o.v;
}

// ---------------------------------------------------------------------------
// f32 [R][Cc] -> bf16 [Cc][R]  (validated)
// ---------------------------------------------------------------------------
__global__ __launch_bounds__(256) void transpose_convert_kernel(
    const float* __restrict__ src, short* __restrict__ dst,
    int R, int Cc)
{
  src += (size_t)blockIdx.z * R * Cc;
  dst += (size_t)blockIdx.z * (size_t)R * Cc;
  __shared__ float tile[64][65];
  int c0 = blockIdx.x * 64, r0 = blockIdx.y * 64;
  int tid = threadIdx.x;
  int tr = tid >> 4, tc = (tid & 15) * 4;
#pragma unroll
  for (int p = 0; p < 4; p++) {
    int r = p * 16 + tr;
    float4 v = *(const float4*)(src + (size_t)(r0 + r) * Cc + c0 + tc);
    tile[r][tc] = v.x; tile[r][tc + 1] = v.y; tile[r][tc + 2] = v.z; tile[r][tc + 3] = v.w;
  }
  __syncthreads();
#pragma unroll
  for (int p = 0; p < 4; p++) {
    int c = p * 16 + tr;
    union { unsigned short us[4]; ushort4 v; } o;
#pragma unroll
    for (int j = 0; j < 4; j++) o.us[j] = f2bf(tile[tc + j][c]);
    *(ushort4*)(dst + (size_t)(c0 + c) * R + r0 + tc) = o.v;
  }
}

// ---------------------------------------------------------------------------
// Real GEMM: byte-identical to round 9 (best measured: 387 us/dispatch).
// ---------------------------------------------------------------------------
#define DECODE_GEOM \
  int flat = blockIdx.x; \
  int e = flat & 7; \
  int s = flat >> 3; \
  int r = s % rows; \
  int t = s / rows; \
  int c, kc; \
  if (MODE == 0) { c = t; kc = 0; } \
  else           { c = t & 3; kc = t >> 2; } \
  int cnt = counts[e]; \
  int row0 = r * 256; \
  if (row0 >= cnt) return; \
  int col0 = c * 256; \
  int tid = threadIdx.x; \
  int w = tid >> 6, l = tid & 63; \
  int wr = w >> 2, wc = w & 3; \
  int rowT = tid & 255, kbT = tid >> 8; \
  (void)w; (void)wr; (void)wc; (void)col0;

#define SETUP_PTRS \
  const short *pA, *pB; \
  if (MODE == 0) { \
    int tok = min(s2t[(size_t)e * cap + row0 + rowT], N - 1); \
    pA = Abase + (size_t)tok * C_DIM; \
    pB = Wt + (size_t)e * (C_DIM * H_DIM) + (size_t)(col0 + rowT) * C_DIM; \
  } else { \
    pA = Abase + ((size_t)e * cap + row0 + rowT) * H_DIM + kc * 1024; \
    pB = Wt + (size_t)e * (C_DIM * H_DIM) + (size_t)(col0 + rowT) * H_DIM + kc * 1024; \
  }

#define STAGE(k0, buf) { \
  gload16(pA + (k0) + kbT * 8,       &As[buf][kbT * 2048 + rowT * 8]); \
  gload16(pA + (k0) + (kbT + 2) * 8, &As[buf][(kbT + 2) * 2048 + rowT * 8]); \
  gload16(pB + (k0) + kbT * 8,       &Bs[buf][kbT * 2048 + rowT * 8]); \
  gload16(pB + (k0) + (kbT + 2) * 8, &Bs[buf][(kbT + 2) * 2048 + rowT * 8]); }

template<int MODE>
__global__ __launch_bounds__(512, 2) void gemm_moe(
    const short* __restrict__ Abase, const short* __restrict__ Wt,
    const int* __restrict__ s2t, const float* __restrict__ gslot,
    const int* __restrict__ counts, void* __restrict__ outp,
    int cap, int N, int rows)
{
  __shared__ short As[3][8192];
  __shared__ short Bs[3][8192];
  DECODE_GEOM;
  SETUP_PTRS;
  const int NS = 32;

  unsigned aB = LDS_U32(As) + (unsigned)((l >> 4) * 4096 + (wr * 128 + (l & 15)) * 16);
  unsigned bB = LDS_U32(Bs) + (unsigned)((l >> 4) * 4096 + (wc * 64 + (l & 15)) * 16);

  f32x4 acc[8][4];
#pragma unroll
  for (int m = 0; m < 8; m++)
#pragma unroll
    for (int n = 0; n < 4; n++) acc[m][n] = 0.f;

  STAGE(0, 0);
  STAGE(32, 1);

  unsigned bufR = 0;
  int bufS = 2;
#pragma unroll 1
  for (int i = 0; i < NS; ++i) {
    if (i == NS - 1) { VMW(0); } else { VMW(4); }
    __builtin_amdgcn_s_barrier();
    __builtin_amdgcn_sched_barrier(0);

    u32x4 af[8], bg[4];
    unsigned aA = aB + bufR, bA = bB + bufR;
    DSR(af[0], aA, 0);    DSR(af[1], aA, 256);  DSR(af[2], aA, 512);  DSR(af[3], aA, 768);
    DSR(af[4], aA, 1024); DSR(af[5], aA, 1280); DSR(af[6], aA, 1536); DSR(af[7], aA, 1792);
    DSR(bg[0], bA, 0);    DSR(bg[1], bA, 256);  DSR(bg[2], bA, 512);  DSR(bg[3], bA, 768);

    if (i + 2 < NS) {
      STAGE((i + 2) * 32, bufS);
      bufS = (bufS == 2) ? 0 : bufS + 1;
    }

    LGKM0;
    __builtin_amdgcn_s_setprio(1);
#pragma unroll
    for (int m = 0; m < 8; m++)
#pragma unroll
      for (int n = 0; n < 4; n++)
        acc[m][n] = mfma16(af[m], bg[n], acc[m][n]);
    __builtin_amdgcn_s_setprio(0);

    bufR = (bufR == 32768u) ? 0u : bufR + 16384u;
  }

  int orow = row0 + wr * 128 + (l >> 4) * 4;
  int ocol = col0 + wc * 64 + (l & 15);
  if (MODE == 0) {
    short* hE = (short*)outp + (size_t)e * cap * H_DIM;
#pragma unroll
    for (int m = 0; m < 8; m++)
#pragma unroll
      for (int rr = 0; rr < 4; rr++) {
        int slot = orow + m * 16 + rr;
        float g = gslot[(size_t)e * cap + slot];
        size_t rb = (size_t)slot * H_DIM + ocol;
#pragma unroll
        for (int n = 0; n < 4; n++) {
          float v = acc[m][n][rr];
          hE[rb + n * 16] = (short)f2bf(g * (v / (1.f + expf(-v))));
        }
      }
  } else {
    float* out = (float*)outp;
#pragma unroll
    for (int m = 0; m < 8; m++)
#pragma unroll
      for (int rr = 0; rr < 4; rr++) {
        int slot = orow + m * 16 + rr;
        int tok = s2t[(size_t)e * cap + slot];
        if (tok < N) {
          float* op = out + (size_t)tok * C_DIM + ocol;
#pragma unroll
          for (int n = 0; n < 4; n++)
            atomicAdd(op + n * 16, acc[m][n][rr]);
        }
      }
  }
}

// ---------------------------------------------------------------------------
// ABLATION KERNELS (round 11): stripped copies of gemm_moe<0>, identical grid
// and address streams, outputs/side-effects into d_ws scratch only.
// ---------------------------------------------------------------------------

// A: staging pipeline only (counted vmcnt + barriers, no ds_read/MFMA).
__global__ __launch_bounds__(512, 2) void abl_stage_bar(
    const short* __restrict__ Abase, const short* __restrict__ Wt,
    const int* __restrict__ s2t, const int* __restrict__ counts,
    int cap, int N, int rows)
{
  constexpr int MODE = 0;
  __shared__ short As[3][8192];
  __shared__ short Bs[3][8192];
  DECODE_GEOM;
  SETUP_PTRS;
  const int NS = 32;
  STAGE(0, 0);
  STAGE(32, 1);
  int bufS = 2;
#pragma unroll 1
  for (int i = 0; i < NS; ++i) {
    if (i == NS - 1) { VMW(0); } else { VMW(4); }
    __builtin_amdgcn_s_barrier();
    __builtin_amdgcn_sched_barrier(0);
    if (i + 2 < NS) {
      STAGE((i + 2) * 32, bufS);
      bufS = (bufS == 2) ? 0 : bufS + 1;
    }
  }
  VMW(0);
}

// B: staging only, NO waits/barriers at all (raw DMA engine rate).
__global__ __launch_bounds__(512, 2) void abl_stage_nobar(
    const short* __restrict__ Abase, const short* __restrict__ Wt,
    const int* __restrict__ s2t, const int* __restrict__ counts,
    int cap, int N, int rows)
{
  constexpr int MODE = 0;
  __shared__ short As[3][8192];
  __shared__ short Bs[3][8192];
  DECODE_GEOM;
  SETUP_PTRS;
  const int NS = 32;
#pragma unroll 1
  for (int i = 0; i < NS; ++i) {
    STAGE(i * 32, (i % 3));
  }
  VMW(0);
}

// C: staging pipeline + asm ds_reads, NO MFMA. Reads kept live via xor-sink.
__global__ __launch_bounds__(512, 2) void abl_dsread(
    const short* __restrict__ Abase, const short* __restrict__ Wt,
    const int* __restrict__ s2t, const int* __restrict__ counts,
    unsigned* __restrict__ sink, int cap, int N, int rows)
{
  constexpr int MODE = 0;
  __shared__ short As[3][8192];
  __shared__ short Bs[3][8192];
  DECODE_GEOM;
  SETUP_PTRS;
  const int NS = 32;
  unsigned aB = LDS_U32(As) + (unsigned)((l >> 4) * 4096 + (wr * 128 + (l & 15)) * 16);
  unsigned bB = LDS_U32(Bs) + (unsigned)((l >> 4) * 4096 + (wc * 64 + (l & 15)) * 16);
  u32x4 keep = {0u, 0u, 0u, 0u};
  STAGE(0, 0);
  STAGE(32, 1);
  unsigned bufR = 0;
  int bufS = 2;
#pragma unroll 1
  for (int i = 0; i < NS; ++i) {
    if (i == NS - 1) { VMW(0); } else { VMW(4); }
    __builtin_amdgcn_s_barrier();
    __builtin_amdgcn_sched_barrier(0);
    u32x4 af[8], bg[4];
    unsigned aA = aB + bufR, bA = bB + bufR;
    DSR(af[0], aA, 0);    DSR(af[1], aA, 256);  DSR(af[2], aA, 512);  DSR(af[3], aA, 768);
    DSR(af[4], aA, 1024); DSR(af[5], aA, 1280); DSR(af[6], aA, 1536); DSR(af[7], aA, 1792);
    DSR(bg[0], bA, 0);    DSR(bg[1], bA, 256);  DSR(bg[2], bA, 512);  DSR(bg[3], bA, 768);
    if (i + 2 < NS) {
      STAGE((i + 2) * 32, bufS);
      bufS = (bufS == 2) ? 0 : bufS + 1;
    }
    LGKM0;
#pragma unroll
    for (int m = 0; m < 8; m++) keep ^= af[m];
#pragma unroll
    for (int n = 0; n < 4; n++) keep ^= bg[n];
    bufR = (bufR == 32768u) ? 0u : bufR + 16384u;
  }
  sink[(size_t)blockIdx.x * 512 + tid] = keep.x ^ keep.y ^ keep.z ^ keep.w;
}

// D: MFMA + barriers only (no vmem, no LDS). acc kept live via scratch store.
__global__ __launch_bounds__(512, 2) void abl_mfma(
    const int* __restrict__ counts, float* __restrict__ sink,
    int cap, int rows)
{
  constexpr int MODE = 0;
  int flat = blockIdx.x;
  int e = flat & 7;
  int s = flat >> 3;
  int r = s % rows;
  (void)MODE; (void)s;
  int cnt = counts[e];
  int row0 = r * 256;
  if (row0 >= cnt) return;
  int tid = threadIdx.x;
  const int NS = 32;

  u32x4 af[8], bg[4];
#pragma unroll
  for (int m = 0; m < 8; m++) af[m] = u32x4{(unsigned)(tid + m), 2u, 3u, 4u};
#pragma unroll
  for (int n = 0; n < 4; n++) bg[n] = u32x4{(unsigned)(tid * 7 + n), 5u, 6u, 7u};

  f32x4 acc[8][4];
#pragma unroll
  for (int m = 0; m < 8; m++)
#pragma unroll
    for (int n = 0; n < 4; n++) acc[m][n] = 0.f;

#pragma unroll 1
  for (int i = 0; i < NS; ++i) {
    __builtin_amdgcn_s_barrier();
    __builtin_amdgcn_sched_barrier(0);
    __builtin_amdgcn_s_setprio(1);
#pragma unroll
    for (int m = 0; m < 8; m++)
#pragma unroll
      for (int n = 0; n < 4; n++)
        acc[m][n] = mfma16(af[m], bg[n], acc[m][n]);
    __builtin_amdgcn_s_setprio(0);
  }
  float sum = 0.f;
#pragma unroll
  for (int m = 0; m < 8; m++)
#pragma unroll
    for (int n = 0; n < 4; n++)
#pragma unroll
      for (int k = 0; k < 4; k++) sum += acc[m][n][k];
  sink[(size_t)blockIdx.x * 512 + tid] = sum;
}

extern "C" void kernel_launch(void* const* d_in, const int* in_sizes, int n_in,
                              void* d_out, int out_size, void* d_ws, size_t ws_size,
                              hipStream_t stream)
{
  const float* x     = (const float*)d_in[0];
  const float* noise = (const float*)d_in[1];
  const float* Wr    = (const float*)d_in[2];
  const float* Wn    = (const float*)d_in[3];
  const float* W1    = (const float*)d_in[4];
  const float* W2    = (const float*)d_in[5];
  float* out = (float*)d_out;

  int N = in_sizes[0] / C_DIM;                        // 8192
  int cap = (int)((double)N * 2.0 / E_NUM * 1.25);    // 2560
  int rows = cap / 256;                               // 10

  size_t off = 0;
  auto alloc = [&](size_t bytes) -> char* {
    char* r = (char*)d_ws + off;
    off += (bytes + 255) & ~(size_t)255;
    return r;
  };
  int2*   idx    = (int2*)alloc((size_t)N * sizeof(int2));
  float2* gates  = (float2*)alloc((size_t)N * sizeof(float2));
  int*    s2t    = (int*)alloc((size_t)E_NUM * cap * sizeof(int));
  float*  gslot  = (float*)alloc((size_t)E_NUM * cap * sizeof(float));
  int*    counts = (int*)alloc(E_NUM * sizeof(int));
  short*  xbf    = (short*)alloc((size_t)N * C_DIM * sizeof(short));
  short*  W1t    = (short*)alloc((size_t)E_NUM * C_DIM * H_DIM * sizeof(short));
  short*  W2t    = (short*)alloc((size_t)E_NUM * C_DIM * H_DIM * sizeof(short));
  short*  h      = (short*)alloc((size_t)E_NUM * cap * H_DIM * sizeof(short));
  unsigned* ablS = (unsigned*)alloc((size_t)1280 * 512 * sizeof(unsigned));
  float*    ablF = (float*)alloc((size_t)1280 * 512 * sizeof(float));
  (void)ws_size;

  hipMemsetAsync(d_out, 0, (size_t)out_size * sizeof(float), stream);
  router_kernel<<<N, 256, 0, stream>>>(x, noise, Wr, Wn, idx, gates, N);
  scan_kernel<<<E_NUM, 256, 0, stream>>>(idx, gates, s2t, gslot, counts, N, cap);
  convert_x_kernel<<<(N * C_DIM / 8 + 255) / 256, 256, 0, stream>>>(x, xbf, N * C_DIM / 8);
  transpose_convert_kernel<<<dim3(H_DIM / 64, C_DIM / 64, E_NUM), 256, 0, stream>>>(
      W1, W1t, C_DIM, H_DIM);
  transpose_convert_kernel<<<dim3(C_DIM / 64, H_DIM / 64, E_NUM), 256, 0, stream>>>(
      W2, W2t, H_DIM, C_DIM);

  // real GEMMs (R9, unchanged)
  gemm_moe<0><<<dim3(E_NUM * rows * (H_DIM / 256)), 512, 0, stream>>>(
      xbf, W1t, s2t, gslot, counts, h, cap, N, rows);
  gemm_moe<1><<<dim3(E_NUM * rows * 4 * 4), 512, 0, stream>>>(
      h, W2t, s2t, gslot, counts, out, cap, N, rows);

  // ---- ablation dispatches (scratch-only; rocprof reads their durations) ----
  dim3 ablGrid(E_NUM * rows * (H_DIM / 256));   // 1280, identical to mlp1
  abl_mfma      <<<ablGrid, 512, 0, stream>>>(counts, ablF, cap, rows);
  abl_stage_bar <<<ablGrid, 512, 0, stream>>>(xbf, W1t, s2t, counts, cap, N, rows);
  abl_stage_nobar<<<ablGrid, 512, 0, stream>>>(xbf, W1t, s2t, counts, cap, N, rows);
  abl_dsread    <<<ablGrid, 512, 0, stream>>>(xbf, W1t, s2t, counts, ablS, cap, N, rows);
}